// Round 4
// baseline (228.504 us; speedup 1.0000x reference)
//
#include <hip/hip_runtime.h>
#include <hip/hip_bf16.h>

// Problem constants
#define B 32
#define T 4096
#define E 1024
#define H 1024

#define CHUNK 128
#define NTC   (T / CHUNK)   // 32 t-chunks

// ws layout (in floats)
// qkv: p=0 -> v, p=1 -> k, p=2 -> q  (matches input order W_value, W_Key, W_Query)
#define ECH        16
#define OFF_QKV    0                                   //  98304
#define OFF_PART1  (3 * B * H)                         //  3*ECH*B*H = 1572864
#define OFF_OPART  (OFF_PART1 + 3 * ECH * B * H)       //  B*NTC*H   = 1048576
#define OFF_MX     (OFF_OPART + B * NTC * H)           //  B*NTC     = 1024
#define OFF_SM     (OFF_MX + B * NTC)                  //  B*NTC     = 1024

__device__ __forceinline__ float wredsum(float v) {
#pragma unroll
    for (int m = 32; m; m >>= 1) v += __shfl_xor(v, m, 64);
    return v;
}
__device__ __forceinline__ float wredmax(float v) {
#pragma unroll
    for (int m = 32; m; m >>= 1) v = fmaxf(v, __shfl_xor(v, m, 64));
    return v;
}

// ---------------------------------------------------------------------------
// Kernel 1: projection partial sums (UNCHANGED from round-3 anchor).
// grid (ECH, 16, 3), block 256.
__global__ void proj_partial(const float* __restrict__ x,
                             const float* __restrict__ Wv,
                             const float* __restrict__ Wk,
                             const float* __restrict__ Wq,
                             float* __restrict__ part) {
    const int ec = blockIdx.x;
    const int hc = blockIdx.y;
    const int p  = blockIdx.z;
    const float* __restrict__ W = (p == 0) ? Wv : ((p == 1) ? Wk : Wq);

    const int wave = threadIdx.x >> 6;
    const int lane = threadIdx.x & 63;
    const int h  = hc * 64 + lane;
    const int b0 = wave * 8;
    const int e0 = ec * 64;

    float acc[8] = {0.f, 0.f, 0.f, 0.f, 0.f, 0.f, 0.f, 0.f};

    for (int eg = 0; eg < 16; ++eg) {
        const int e = e0 + eg * 4;
        const float w0 = W[(size_t)(e + 0) * H + h];
        const float w1 = W[(size_t)(e + 1) * H + h];
        const float w2 = W[(size_t)(e + 2) * H + h];
        const float w3 = W[(size_t)(e + 3) * H + h];
#pragma unroll
        for (int j = 0; j < 8; ++j) {
            const float4 xv = *reinterpret_cast<const float4*>(&x[(b0 + j) * E + e]);
            acc[j] += xv.x * w0 + xv.y * w1 + xv.z * w2 + xv.w * w3;
        }
    }
#pragma unroll
    for (int j = 0; j < 8; ++j) {
        part[((size_t)(p * ECH + ec) * B + (b0 + j)) * H + h] = acc[j];
    }
}

// ---------------------------------------------------------------------------
// Kernel 2: reduce projection partials -> qkv (UNCHANGED). grid 384, block 256.
__global__ void proj_reduce(const float* __restrict__ part,
                            float* __restrict__ qkv) {
    const int idx = blockIdx.x * 256 + threadIdx.x;
    const int p = idx >> 15;
    const int r = idx & 32767;
    float s = 0.f;
#pragma unroll
    for (int ec = 0; ec < ECH; ++ec)
        s += part[(size_t)(p * ECH + ec) * (B * H) + r];
    qkv[(size_t)p * (B * H) + r] = s;
}

// ---------------------------------------------------------------------------
// Kernel 3: split-K flash decode. grid (NTC, B), block 256 (4 waves).
// Per block: chunk of 128 t's. Phase A: scores (wave shuffle-reduce, q in regs).
// Phase B: local softmax (max/exp/sum) in LDS. Phase C: PV accumulate.
__global__ __launch_bounds__(256) void flash_kernel(const float* __restrict__ kc,
                                                    const float* __restrict__ vc,
                                                    const float* __restrict__ q,
                                                    float* __restrict__ o_part,
                                                    float* __restrict__ mx_part,
                                                    float* __restrict__ sm_part) {
    __shared__ float s_sc[CHUNK];
    __shared__ float red[8];
    const int tc = blockIdx.x, b = blockIdx.y;
    const int tid  = threadIdx.x;
    const int wave = tid >> 6;
    const int lane = tid & 63;
    const int t0 = tc * CHUNK;

    // q in registers (L2-resident, 4 KB/batch)
    const float4* __restrict__ q4 = reinterpret_cast<const float4*>(q + (size_t)b * H);
    float4 qv[4];
#pragma unroll
    for (int g = 0; g < 4; ++g) qv[g] = q4[g * 64 + lane];

    // Phase A: scores for 32 rows per wave, 2 at a time (8 loads in flight)
    for (int r = 0; r < 32; r += 2) {
        const int t = t0 + wave * 32 + r;
        const float4* __restrict__ r0 =
            reinterpret_cast<const float4*>(kc + ((size_t)b * T + t) * H);
        const float4* __restrict__ r1 =
            reinterpret_cast<const float4*>(kc + ((size_t)b * T + t + 1) * H);
        float a0 = 0.f, a1 = 0.f;
#pragma unroll
        for (int g = 0; g < 4; ++g) {
            const float4 k0 = r0[g * 64 + lane];
            const float4 k1 = r1[g * 64 + lane];
            a0 += k0.x * qv[g].x + k0.y * qv[g].y + k0.z * qv[g].z + k0.w * qv[g].w;
            a1 += k1.x * qv[g].x + k1.y * qv[g].y + k1.z * qv[g].z + k1.w * qv[g].w;
        }
        a0 = wredsum(a0);
        a1 = wredsum(a1);
        if (lane == 0) {
            s_sc[wave * 32 + r]     = a0;
            s_sc[wave * 32 + r + 1] = a1;
        }
    }
    __syncthreads();

    // Phase B: local max
    float m = (tid < CHUNK) ? s_sc[tid] : -INFINITY;
    m = wredmax(m);
    if (lane == 0) red[wave] = m;
    __syncthreads();
    m = fmaxf(fmaxf(red[0], red[1]), fmaxf(red[2], red[3]));

    // exp + local sum (same-slot read/write per thread: no race)
    float e = 0.f;
    if (tid < CHUNK) {
        e = expf(s_sc[tid] - m);
        s_sc[tid] = e;
    }
    float s = wredsum(e);
    if (lane == 0) red[4 + wave] = s;
    __syncthreads();   // also makes s_sc exp values visible to all
    const float sum = red[4] + red[5] + red[6] + red[7];
    if (tid == 0) {
        mx_part[(size_t)b * NTC + tc] = m;
        sm_part[(size_t)b * NTC + tc] = sum;
    }

    // Phase C: PV accumulate; thread owns a float4 of h
    const float4* __restrict__ vrow =
        reinterpret_cast<const float4*>(vc + ((size_t)b * T + t0) * H);
    float4 acc = {0.f, 0.f, 0.f, 0.f};
#pragma unroll 4
    for (int t = 0; t < CHUNK; ++t) {
        const float a = s_sc[t];
        const float4 vv = vrow[(size_t)t * 256 + tid];
        acc.x += a * vv.x; acc.y += a * vv.y;
        acc.z += a * vv.z; acc.w += a * vv.w;
    }
    reinterpret_cast<float4*>(o_part + ((size_t)b * NTC + tc) * H)[tid] = acc;
}

// ---------------------------------------------------------------------------
// Kernel 4: LSE combine + appended token + scale + residual.
// grid (H/256, B), block 256; thread owns one h.
__global__ __launch_bounds__(256) void combine_kernel(const float* __restrict__ o_part,
                                                      const float* __restrict__ mx_part,
                                                      const float* __restrict__ sm_part,
                                                      const float* __restrict__ qkv,
                                                      const float* __restrict__ x,
                                                      float* __restrict__ out) {
    __shared__ float red[256];
    __shared__ float w_s[NTC];
    const int b = blockIdx.y;
    const int h = blockIdx.x * 256 + threadIdx.x;
    const int tid = threadIdx.x;

    // appended-token score s_last = dot(q[b], k[b])
    const float4 qv = reinterpret_cast<const float4*>(qkv + 2 * (B * H) + (size_t)b * H)[tid];
    const float4 kv = reinterpret_cast<const float4*>(qkv + 1 * (B * H) + (size_t)b * H)[tid];
    red[tid] = qv.x * kv.x + qv.y * kv.y + qv.z * kv.z + qv.w * kv.w;
    __syncthreads();
    for (int s = 128; s; s >>= 1) {
        if (tid < s) red[tid] += red[tid + s];
        __syncthreads();
    }
    const float s_last = red[0];
    __syncthreads();

    // global max M over chunk maxes and s_last
    red[tid] = (tid < NTC) ? mx_part[(size_t)b * NTC + tid] : -INFINITY;
    __syncthreads();
    for (int s = 128; s; s >>= 1) {
        if (tid < s) red[tid] = fmaxf(red[tid], red[tid + s]);
        __syncthreads();
    }
    const float M = fmaxf(red[0], s_last);
    __syncthreads();

    // chunk weights and denom
    float dpart = 0.f;
    if (tid < NTC) {
        const float w = expf(mx_part[(size_t)b * NTC + tid] - M);
        w_s[tid] = w;
        dpart = sm_part[(size_t)b * NTC + tid] * w;
    }
    red[tid] = dpart;
    __syncthreads();
    for (int s = 128; s; s >>= 1) {
        if (tid < s) red[tid] += red[tid + s];
        __syncthreads();
    }
    const float e_last = expf(s_last - M);
    const float denom = red[0] + e_last;

    // combine chunk partials
    float o = 0.f;
#pragma unroll
    for (int c = 0; c < NTC; ++c)
        o += o_part[((size_t)b * NTC + c) * H + h] * w_s[c];
    o += e_last * qkv[(size_t)b * H + h];          // p=0 slot: value projection
    out[(size_t)b * H + h] = o / denom * (1.f / 32.f) + x[(size_t)b * H + h];
}

// ---------------------------------------------------------------------------
extern "C" void kernel_launch(void* const* d_in, const int* in_sizes, int n_in,
                              void* d_out, int out_size, void* d_ws, size_t ws_size,
                              hipStream_t stream) {
    const float* x  = (const float*)d_in[0];
    const float* kc = (const float*)d_in[1];
    const float* vc = (const float*)d_in[2];
    const float* Wv = (const float*)d_in[3];
    const float* Wk = (const float*)d_in[4];
    const float* Wq = (const float*)d_in[5];
    float* out = (float*)d_out;
    float* ws  = (float*)d_ws;

    float* qkv    = ws + OFF_QKV;
    float* part1  = ws + OFF_PART1;
    float* o_part = ws + OFF_OPART;
    float* mx     = ws + OFF_MX;
    float* sm     = ws + OFF_SM;

    hipLaunchKernelGGL(proj_partial, dim3(ECH, 16, 3), dim3(256), 0, stream,
                       x, Wv, Wk, Wq, part1);
    hipLaunchKernelGGL(proj_reduce, dim3(384), dim3(256), 0, stream,
                       part1, qkv);
    hipLaunchKernelGGL(flash_kernel, dim3(NTC, B), dim3(256), 0, stream,
                       kc, vc, qkv + 2 * (B * H), o_part, mx, sm);
    hipLaunchKernelGGL(combine_kernel, dim3(H / 256, B), dim3(256), 0, stream,
                       o_part, mx, sm, qkv, x, out);
}